// Round 1
// baseline (470.426 us; speedup 1.0000x reference)
//
#include <hip/hip_runtime.h>

// 3x3 VALID cross-correlation (XLA conv semantics: no kernel flip) + bias.
// x: 8192x8192 fp32, weight: 3x3 fp32, bias: scalar. out: 8190x8190 fp32.
//
// Memory-bound problem: 512 MiB ideal traffic -> ~85us floor at 6.3 TB/s.
// Each thread computes a 16-row x 4-col output strip streaming 18 input rows
// through registers (vertical read amplification 18/16 = 1.125x).

#define IH 8192
#define IW 8192
#define OH 8190
#define OW 8190
#define RPT 16   // output rows per thread

// Output row stride (8190) is not a multiple of 4, so float4 stores are only
// 8B-aligned on odd rows -> use an alignment-4 vector type for safe stores.
typedef float float4u __attribute__((ext_vector_type(4), aligned(4)));

__global__ __launch_bounds__(256) void conv2d_3x3_kernel(
    const float* __restrict__ x,
    const float* __restrict__ w,
    const float* __restrict__ bias,
    float* __restrict__ out)
{
    const int c0 = 4 * (blockIdx.x * 256 + threadIdx.x);  // max 8188 < OW
    const int r0 = blockIdx.y * RPT;

    const float w00 = w[0], w01 = w[1], w02 = w[2];
    const float w10 = w[3], w11 = w[4], w12 = w[5];
    const float w20 = w[6], w21 = w[7], w22 = w[8];
    const float bv = bias[0];

    float acc[RPT][4];
#pragma unroll
    for (int d = 0; d < RPT; ++d)
#pragma unroll
        for (int j = 0; j < 4; ++j) acc[d][j] = 0.0f;

    // Stream input rows r0 .. r0+RPT+1. Input row i contributes:
    //   kernel row 0 -> output row i, row 1 -> i-1, row 2 -> i-2.
#pragma unroll
    for (int d = 0; d < RPT + 2; ++d) {
        const int i = r0 + d;
        if (i >= IH) break;
        const float* rp = x + (size_t)i * IW + c0;

        float vv[6];
        if (c0 + 5 < IW) {
            // c0 is a multiple of 4 -> rp is 16B aligned, rp+4 is 8B aligned.
            const float4 f = *(const float4*)rp;
            const float2 g = *(const float2*)(rp + 4);
            vv[0] = f.x; vv[1] = f.y; vv[2] = f.z; vv[3] = f.w;
            vv[4] = g.x; vv[5] = g.y;
        } else {
            // Only the last column-group (c0 == 8188) lands here.
            vv[0] = rp[0]; vv[1] = rp[1]; vv[2] = rp[2]; vv[3] = rp[3];
            vv[4] = (c0 + 4 < IW) ? rp[4] : 0.0f;
            vv[5] = (c0 + 5 < IW) ? rp[5] : 0.0f;
        }

        if (d < RPT) {
#pragma unroll
            for (int j = 0; j < 4; ++j)
                acc[d][j] += w00 * vv[j] + w01 * vv[j + 1] + w02 * vv[j + 2];
        }
        if (d >= 1 && d - 1 < RPT) {
#pragma unroll
            for (int j = 0; j < 4; ++j)
                acc[d - 1][j] += w10 * vv[j] + w11 * vv[j + 1] + w12 * vv[j + 2];
        }
        if (d >= 2) {
#pragma unroll
            for (int j = 0; j < 4; ++j)
                acc[d - 2][j] += w20 * vv[j] + w21 * vv[j + 1] + w22 * vv[j + 2];
        }
    }

#pragma unroll
    for (int d = 0; d < RPT; ++d) {
        const int r = r0 + d;
        if (r >= OH) break;
        const float o0 = acc[d][0] + bv;
        const float o1 = acc[d][1] + bv;
        const float o2 = acc[d][2] + bv;
        const float o3 = acc[d][3] + bv;
        float* op = out + (size_t)r * OW + c0;
        if (c0 + 4 <= OW) {
            float4u o;
            o.x = o0; o.y = o1; o.z = o2; o.w = o3;
            *(float4u*)op = o;
        } else {
            // Last column-group: cols 8188, 8189 valid only.
            if (c0 + 0 < OW) op[0] = o0;
            if (c0 + 1 < OW) op[1] = o1;
            if (c0 + 2 < OW) op[2] = o2;
            if (c0 + 3 < OW) op[3] = o3;
        }
    }
}

extern "C" void kernel_launch(void* const* d_in, const int* in_sizes, int n_in,
                              void* d_out, int out_size, void* d_ws, size_t ws_size,
                              hipStream_t stream) {
    const float* x  = (const float*)d_in[0];
    const float* w  = (const float*)d_in[1];
    const float* b  = (const float*)d_in[2];
    float* out      = (float*)d_out;

    dim3 block(256, 1, 1);
    dim3 grid(IW / 4 / 256,               // 8 column-group blocks
              (OH + RPT - 1) / RPT, 1);   // 512 row blocks
    conv2d_3x3_kernel<<<grid, block, 0, stream>>>(x, w, b, out);
}

// Round 2
// 433.861 us; speedup vs baseline: 1.0843x; 1.0843x over previous
//
#include <hip/hip_runtime.h>

// 3x3 VALID cross-correlation (XLA conv: no kernel flip) + bias.
// x: 8192x8192 fp32, w: 3x3, bias scalar -> out: 8190x8190 fp32.
//
// Memory-bound: ideal traffic = 256 MiB read + 256 MiB write -> ~85us floor
// at 6.3 TB/s. Each thread: 16-row x 4-col output strip, streaming 18 input
// rows through registers (read amplification 18/16 = 1.125x).
//
// R1 fix: previous version had runtime `break` inside #pragma unroll loops ->
// suspected de-unroll -> runtime-indexed acc[] -> scratch spill (470us).
// Now: constant trip counts, no breaks, branchless edge handling; all acc
// indices are compile-time constants.

#define IH 8192
#define IW 8192
#define OH 8190
#define OW 8190
#define RPT 16   // output rows per thread

// Output row stride 8190 -> odd rows only 8B-aligned; alignment-4 vec type.
typedef float float4u __attribute__((ext_vector_type(4), aligned(4)));

__global__ __launch_bounds__(256) void conv2d_3x3_kernel(
    const float* __restrict__ x,
    const float* __restrict__ w,
    const float* __restrict__ bias,
    float* __restrict__ out)
{
    const int c0 = 4 * (blockIdx.x * 256 + threadIdx.x);  // 0..8188, mult of 4
    const int r0 = blockIdx.y * RPT;
    const bool tail = (c0 + 6 > IW);  // only the single lane with c0 == 8188

    const float w00 = w[0], w01 = w[1], w02 = w[2];
    const float w10 = w[3], w11 = w[4], w12 = w[5];
    const float w20 = w[6], w21 = w[7], w22 = w[8];
    const float bv = bias[0];

    float acc[RPT][4];
#pragma unroll
    for (int d = 0; d < RPT; ++d)
#pragma unroll
        for (int j = 0; j < 4; ++j) acc[d][j] = 0.0f;

    // Branchless tail handling: the float2 companion load sits at +4 floats
    // normally; for the tail lane shift it to -2 (stays in-bounds, 8B aligned)
    // and zero-select the values. Tail garbage only feeds masked output cols.
    const int g_off = tail ? -2 : 4;

    // Stream input rows r0 .. r0+17 (constant trip count -> full unroll).
    // Row index clamped to IH-1 (wave-uniform): clamped rows only contribute
    // to output rows >= OH, which are masked at store.
#pragma unroll
    for (int d = 0; d < RPT + 2; ++d) {
        int i = r0 + d;
        i = (i < IH) ? i : (IH - 1);
        const float* rp = x + (size_t)i * IW + c0;

        const float4 f = *(const float4*)rp;            // 16B aligned
        const float2 g = *(const float2*)(rp + g_off);  // 8B aligned

        float vv[6];
        vv[0] = f.x; vv[1] = f.y; vv[2] = f.z; vv[3] = f.w;
        vv[4] = tail ? 0.0f : g.x;
        vv[5] = tail ? 0.0f : g.y;

        // Input row d contributes: kernel row 0 -> out row d,
        // kernel row 1 -> out row d-1, kernel row 2 -> out row d-2.
        if (d < RPT) {
#pragma unroll
            for (int j = 0; j < 4; ++j)
                acc[d][j] += w00 * vv[j] + w01 * vv[j + 1] + w02 * vv[j + 2];
        }
        if (d >= 1 && d - 1 < RPT) {
#pragma unroll
            for (int j = 0; j < 4; ++j)
                acc[d - 1][j] += w10 * vv[j] + w11 * vv[j + 1] + w12 * vv[j + 2];
        }
        if (d >= 2) {
#pragma unroll
            for (int j = 0; j < 4; ++j)
                acc[d - 2][j] += w20 * vv[j] + w21 * vv[j + 1] + w22 * vv[j + 2];
        }
    }

#pragma unroll
    for (int d = 0; d < RPT; ++d) {
        const int r = r0 + d;
        if (r < OH) {  // wave-uniform (r depends only on blockIdx.y)
            float* op = out + (size_t)r * OW + c0;
            const float o0 = acc[d][0] + bv;
            const float o1 = acc[d][1] + bv;
            const float o2 = acc[d][2] + bv;
            const float o3 = acc[d][3] + bv;
            if (!tail) {
                float4u o;
                o.x = o0; o.y = o1; o.z = o2; o.w = o3;
                *(float4u*)op = o;
            } else {
                // c0 == 8188: only cols 8188, 8189 are valid.
                op[0] = o0;
                op[1] = o1;
            }
        }
    }
}

extern "C" void kernel_launch(void* const* d_in, const int* in_sizes, int n_in,
                              void* d_out, int out_size, void* d_ws, size_t ws_size,
                              hipStream_t stream) {
    const float* x = (const float*)d_in[0];
    const float* w = (const float*)d_in[1];
    const float* b = (const float*)d_in[2];
    float* out     = (float*)d_out;

    dim3 block(256, 1, 1);
    dim3 grid(IW / 4 / 256,               // 8 column-group blocks
              (OH + RPT - 1) / RPT, 1);   // 512 row blocks
    conv2d_3x3_kernel<<<grid, block, 0, stream>>>(x, w, b, out);
}